// Round 9
// baseline (1977.697 us; speedup 1.0000x reference)
//
#include <hip/hip_runtime.h>
#include <hip/hip_cooperative_groups.h>
namespace cg = cooperative_groups;

#define THREADS 256
#define MS 128   // message row stride in shorts (256 B, cache-line aligned)

typedef __bf16 bf16x8 __attribute__((ext_vector_type(8)));
typedef float f32x4 __attribute__((ext_vector_type(4)));
typedef float f32x4u __attribute__((ext_vector_type(4), aligned(4)));

__device__ __forceinline__ unsigned short f2b(float x) {
    unsigned int u = __float_as_uint(x);
    u = (u + 0x7FFFu + ((u >> 16) & 1u)) >> 16;
    return (unsigned short)u;
}
__device__ __forceinline__ float b2f(unsigned short h) {
    return __uint_as_float(((unsigned int)h) << 16);
}
__device__ __forceinline__ bf16x8 as_bf(uint4 q) {
    union { uint4 q; bf16x8 v; } u; u.q = q; return u.v;
}

// ================= shared device bodies (used by both paths) =================

// lane l, reg j -> B[k = kc*32 + (l>>4)*8 + j][n = nt*16 + (l&15)]
__device__ __forceinline__ void pack_body(const float* __restrict__ W,
                                          unsigned short* __restrict__ out,
                                          int K, int bid, int l)
{
    int kc = bid / 7, nt = bid - kc * 7;
    int k0 = kc * 32 + (l >> 4) * 8;
    int n = nt * 16 + (l & 15);
    unsigned short v[8];
    #pragma unroll
    for (int j = 0; j < 8; ++j) {
        int k = k0 + j;
        float x = (k < K && n < 100) ? W[(size_t)k * 100 + n] : 0.f;
        v[j] = f2b(x);
    }
    *(uint4*)&out[((size_t)bid * 64 + l) * 8] = *(uint4*)v;
}

// W_o permuted k: k<100 -> row 133+k (amsg), 100..111 zero, 112..244 -> row k-112 (f_atoms)
__device__ __forceinline__ void pack_wo_body(const float* __restrict__ W,
                                             unsigned short* __restrict__ out,
                                             int bid, int l)
{
    int kc = bid / 7, nt = bid - kc * 7;
    int k0 = kc * 32 + (l >> 4) * 8;
    int n = nt * 16 + (l & 15);
    unsigned short v[8];
    #pragma unroll
    for (int j = 0; j < 8; ++j) {
        int k = k0 + j;
        float x = 0.f;
        if (n < 100) {
            if (k < 100)                  x = W[(size_t)(133 + k) * 100 + n];
            else if (k >= 112 && k < 245) x = W[(size_t)(k - 112) * 100 + n];
        }
        v[j] = f2b(x);
    }
    *(uint4*)&out[((size_t)bid * 64 + l) * 8] = *(uint4*)v;
}

__device__ __forceinline__ void prep_item(int i,
    const float* __restrict__ Wi, const float* __restrict__ Wh, const float* __restrict__ Wo,
    unsigned short* __restrict__ wfi, unsigned short* __restrict__ wfh,
    unsigned short* __restrict__ wfo)
{
    int bid = i >> 6, l = i & 63;
    if (bid < 35)      pack_body(Wi, wfi, 147, bid, l);
    else if (bid < 63) pack_body(Wh, wfh, 100, bid - 35, l);
    else               pack_wo_body(Wo, wfo, bid - 63, l);
}

// one (atom, chunk) work item of the 6-neighbor gather-sum
__device__ __forceinline__ void gather_item(int t,
    const unsigned short* __restrict__ msg, const int* __restrict__ a2b,
    unsigned short* __restrict__ amsg)
{
    int a = t >> 4;
    int c = t & 15;
    if (c >= 14) {
        *(uint4*)&amsg[(size_t)a * MS + c * 8] = make_uint4(0u, 0u, 0u, 0u);
        return;
    }
    const int* nb = a2b + (size_t)a * 6;
    float s[8];
    #pragma unroll
    for (int e = 0; e < 8; ++e) s[e] = 0.f;
    #pragma unroll
    for (int j = 0; j < 6; ++j) {
        uint4 v = *(const uint4*)&msg[(size_t)nb[j] * MS + c * 8];
        const unsigned short* pv = (const unsigned short*)&v;
        #pragma unroll
        for (int e = 0; e < 8; ++e) s[e] += b2f(pv[e]);
    }
    unsigned short r[8];
    #pragma unroll
    for (int e = 0; e < 8; ++e) r[e] = f2b(s[e]);
    *(uint4*)&amsg[(size_t)a * MS + c * 8] = *(uint4*)r;
}

// ---- gemm_in tile: inp = relu(f_bonds @ W_i), 64 rows ----
__device__ __forceinline__ void gemm_in_tile(int row0, int tid,
    const float* __restrict__ fb, const unsigned short* __restrict__ wf,
    unsigned short* __restrict__ Y, int M, char* smem)
{
    constexpr int KS = 168;
    unsigned short* Xs = (unsigned short*)smem;
    unsigned short* Os = (unsigned short*)smem;
    const int l = tid & 63, w = tid >> 6;
    const int quad = l >> 4, c15 = l & 15;

    for (int t = tid; t < 64 * 20; t += THREADS) {
        int rl = t / 20, c = t - rl * 20;
        int rr = min(row0 + rl, M - 1);
        const float* rowp = fb + (size_t)rr * 147 + c * 8;
        unsigned short tt[8];
        if (c < 18) {
            f32x4u x0 = *(const f32x4u*)(rowp);
            f32x4u x1 = *(const f32x4u*)(rowp + 4);
            #pragma unroll
            for (int e = 0; e < 4; ++e) { tt[e] = f2b(x0[e]); tt[4 + e] = f2b(x1[e]); }
        } else if (c == 18) {
            #pragma unroll
            for (int j = 0; j < 8; ++j)
                tt[j] = (j < 3) ? f2b(rowp[j]) : (unsigned short)0;
        } else {
            #pragma unroll
            for (int j = 0; j < 8; ++j) tt[j] = 0;
        }
        *(uint4*)&Xs[(size_t)rl * KS + c * 8] = *(uint4*)tt;
    }
    __syncthreads();

    f32x4 acc[7];
    #pragma unroll
    for (int nt = 0; nt < 7; ++nt) acc[nt] = (f32x4){0.f, 0.f, 0.f, 0.f};
    const unsigned short* xrow = Xs + (size_t)(w * 16 + c15) * KS + quad * 8;
    #pragma unroll
    for (int kc = 0; kc < 5; ++kc) {
        bf16x8 av = *(const bf16x8*)(xrow + kc * 32);
        #pragma unroll
        for (int nt = 0; nt < 7; ++nt) {
            uint4 bq = *(const uint4*)&wf[((size_t)(kc * 7 + nt) * 64 + l) * 8];
            acc[nt] = __builtin_amdgcn_mfma_f32_16x16x32_bf16(av, as_bf(bq), acc[nt], 0, 0, 0);
        }
    }
    __syncthreads();

    #pragma unroll
    for (int nt = 0; nt < 7; ++nt)
        #pragma unroll
        for (int reg = 0; reg < 4; ++reg)
            Os[(w * 16 + quad * 4 + reg) * 136 + nt * 16 + c15] = f2b(fmaxf(acc[nt][reg], 0.f));
    __syncthreads();

    for (int t = tid; t < 64 * 16; t += THREADS) {
        int rl = t >> 4, c = t & 15;
        int rr = row0 + rl;
        if (rr < M) {
            uint4 o = (c < 14) ? *(const uint4*)&Os[rl * 136 + c * 8]
                               : make_uint4(0u, 0u, 0u, 0u);
            *(uint4*)&Y[(size_t)rr * MS + c * 8] = o;
        }
    }
    __syncthreads();   // smem reused by next tile / next phase
}

// ---- gemm_msg tile: message = relu(bias + amsg[b2a]@W - msg[b2revb]@W) ----
__device__ __forceinline__ void gemm_msg_tile(int row0, int tid,
    const unsigned short* __restrict__ amsg, const unsigned short* __restrict__ msg,
    const int* __restrict__ b2a, const int* __restrict__ b2revb,
    const unsigned short* __restrict__ wf, const unsigned short* __restrict__ bias,
    unsigned short* __restrict__ Y, int M, int last, char* smem)
{
    unsigned short* Os = (unsigned short*)smem;
    const int l = tid & 63, w = tid >> 6;
    const int quad = l >> 4, c15 = l & 15;
    const int rc = min(row0 + w * 16 + c15, M - 1);
    const int iA = b2a[rc], iB = b2revb[rc];
    const unsigned short* pa = amsg + (size_t)iA * MS + quad * 8;
    const unsigned short* pb = msg  + (size_t)iB * MS + quad * 8;

    uint4 a1[4], a2[4];
    #pragma unroll
    for (int kc = 0; kc < 4; ++kc) {
        a1[kc] = *(const uint4*)(pa + kc * 32);
        a2[kc] = *(const uint4*)(pb + kc * 32);
    }

    f32x4 acc1[7], acc2[7];
    #pragma unroll
    for (int nt = 0; nt < 7; ++nt) {
        acc1[nt] = (f32x4){0.f, 0.f, 0.f, 0.f};
        acc2[nt] = (f32x4){0.f, 0.f, 0.f, 0.f};
    }
    #pragma unroll
    for (int kc = 0; kc < 4; ++kc) {
        #pragma unroll
        for (int nt = 0; nt < 7; ++nt) {
            uint4 bq = *(const uint4*)&wf[((size_t)(kc * 7 + nt) * 64 + l) * 8];
            acc1[nt] = __builtin_amdgcn_mfma_f32_16x16x32_bf16(as_bf(a1[kc]), as_bf(bq), acc1[nt], 0, 0, 0);
            acc2[nt] = __builtin_amdgcn_mfma_f32_16x16x32_bf16(as_bf(a2[kc]), as_bf(bq), acc2[nt], 0, 0, 0);
        }
    }

    #pragma unroll
    for (int nt = 0; nt < 7; ++nt)
        #pragma unroll
        for (int reg = 0; reg < 4; ++reg)
            Os[(w * 16 + quad * 4 + reg) * 136 + nt * 16 + c15] = f2b(acc1[nt][reg] - acc2[nt][reg]);
    __syncthreads();

    for (int t = tid; t < 64 * 16; t += THREADS) {
        int rl = t >> 4, c = t & 15;
        int rr = row0 + rl;
        if (rr >= M) continue;
        if (c < 14) {
            uint4 o = *(const uint4*)&Os[rl * 136 + c * 8];
            uint4 bq = *(const uint4*)&bias[(size_t)rr * MS + c * 8];
            const unsigned short* po = (const unsigned short*)&o;
            const unsigned short* pq = (const unsigned short*)&bq;
            unsigned short res[8];
            #pragma unroll
            for (int e = 0; e < 8; ++e)
                res[e] = f2b(fmaxf(b2f(po[e]) + b2f(pq[e]), 0.f));
            *(uint4*)&Y[(size_t)rr * MS + c * 8] = *(uint4*)res;
        } else if (!last) {
            *(uint4*)&Y[(size_t)rr * MS + c * 8] = make_uint4(0u, 0u, 0u, 0u);
        }
    }
    __syncthreads();
}

// ---- gemm_out tile: atom_h + fused gather + per-molecule atomics ----
__device__ __forceinline__ void gemm_out_tile(int row0, int tid,
    const float* __restrict__ fa, const unsigned short* __restrict__ msg,
    const int* __restrict__ a2b, const unsigned short* __restrict__ wf,
    const int* __restrict__ mol_id, float* __restrict__ Y,
    float* __restrict__ out_mol, int M, char* smem, int* mids)
{
    constexpr int XSS = 136;
    unsigned short* Xs = (unsigned short*)smem;
    float* Os = (float*)smem;
    const int l = tid & 63, w = tid >> 6;
    const int quad = l >> 4, c15 = l & 15;

    if (tid < 64) {
        int rr = row0 + tid;
        mids[tid] = (rr < M) ? mol_id[rr] : -1;
    }

    uint4 af[5];
    {
        const int r = w * 16 + c15;
        const int rr = min(row0 + r, M - 1);
        const float* fap = fa + (size_t)rr * 133;
        #pragma unroll
        for (int kk = 0; kk < 5; ++kk) {
            int col0 = (kk + 3) * 32 + quad * 8 - 112;
            unsigned short tt[8];
            if (col0 >= 0 && col0 + 7 < 133) {
                f32x4u x0 = *(const f32x4u*)(fap + col0);
                f32x4u x1 = *(const f32x4u*)(fap + col0 + 4);
                #pragma unroll
                for (int e = 0; e < 4; ++e) { tt[e] = f2b(x0[e]); tt[4 + e] = f2b(x1[e]); }
            } else {
                #pragma unroll
                for (int j = 0; j < 8; ++j) {
                    int cc = col0 + j;
                    tt[j] = (cc >= 0 && cc < 133) ? f2b(fap[cc]) : (unsigned short)0;
                }
            }
            af[kk] = *(uint4*)tt;
        }
    }

    for (int t = tid; t < 64 * 16; t += THREADS) {
        int rl = t >> 4, c = t & 15;
        int rr = min(row0 + rl, M - 1);
        uint4 o = make_uint4(0u, 0u, 0u, 0u);
        if (c < 14) {
            const int* nb = a2b + (size_t)rr * 6;
            float s[8];
            #pragma unroll
            for (int e = 0; e < 8; ++e) s[e] = 0.f;
            #pragma unroll
            for (int j = 0; j < 6; ++j) {
                uint4 v = *(const uint4*)&msg[(size_t)nb[j] * MS + c * 8];
                const unsigned short* pv = (const unsigned short*)&v;
                #pragma unroll
                for (int e = 0; e < 8; ++e) s[e] += b2f(pv[e]);
            }
            unsigned short r8[8];
            #pragma unroll
            for (int e = 0; e < 8; ++e) r8[e] = f2b(s[e]);
            o = *(uint4*)r8;
        }
        *(uint4*)&Xs[rl * XSS + c * 8] = o;
    }
    __syncthreads();

    f32x4 acc[7];
    #pragma unroll
    for (int nt = 0; nt < 7; ++nt) acc[nt] = (f32x4){0.f, 0.f, 0.f, 0.f};
    const unsigned short* xrow = Xs + (size_t)(w * 16 + c15) * XSS + quad * 8;
    #pragma unroll
    for (int kc = 0; kc < 8; ++kc) {
        bf16x8 av;
        if (kc < 3)       av = *(const bf16x8*)(xrow + kc * 32);
        else if (kc == 3) av = (quad < 2) ? *(const bf16x8*)(xrow + 3 * 32)
                                          : as_bf(af[0]);
        else              av = as_bf(af[kc - 3]);
        #pragma unroll
        for (int nt = 0; nt < 7; ++nt) {
            uint4 bq = *(const uint4*)&wf[((size_t)(kc * 7 + nt) * 64 + l) * 8];
            acc[nt] = __builtin_amdgcn_mfma_f32_16x16x32_bf16(av, as_bf(bq), acc[nt], 0, 0, 0);
        }
    }
    __syncthreads();

    #pragma unroll
    for (int nt = 0; nt < 7; ++nt) {
        int n = nt * 16 + c15;
        if (n < 100) {
            #pragma unroll
            for (int reg = 0; reg < 4; ++reg)
                Os[(w * 16 + quad * 4 + reg) * 100 + n] = fmaxf(acc[nt][reg], 0.f);
        }
    }
    __syncthreads();

    for (int t = tid; t < 64 * 25; t += THREADS) {
        int rl = t / 25, c = t - rl * 25;
        int rr = row0 + rl;
        if (rr < M)
            *(f32x4*)&Y[(size_t)rr * 100 + c * 4] = *(const f32x4*)&Os[rl * 100 + c * 4];
    }

    if (tid < 100) {
        int c = tid;
        float s = 0.f;
        int cur = mids[0];
        #pragma unroll 1
        for (int rl = 0; rl < 64; ++rl) {
            int mid = mids[rl];
            if (mid != cur) {
                if (cur >= 0) atomicAdd(&out_mol[(size_t)cur * 108 + c], s);
                s = 0.f;
                cur = mid;
            }
            if (mid < 0) break;
            s += Os[rl * 100 + c];
        }
        if (cur >= 0) atomicAdd(&out_mol[(size_t)cur * 108 + c], s);
    }
    __syncthreads();
}

__device__ __forceinline__ void finalize_item(int m, int c,
    float* __restrict__ out_mol, const float* __restrict__ f_mol,
    const int* __restrict__ mol_id, int n_atoms)
{
    int lo = 0, hi = n_atoms;
    while (lo < hi) { int mid = (lo + hi) >> 1; if (mol_id[mid] < m) lo = mid + 1; else hi = mid; }
    int lo2 = lo, hi2 = n_atoms;
    while (lo2 < hi2) { int mid = (lo2 + hi2) >> 1; if (mol_id[mid] < m + 1) lo2 = mid + 1; else hi2 = mid; }
    float inv = 1.0f / fmaxf((float)(lo2 - lo), 1.0f);
    if (c < 100) {
        out_mol[(size_t)m * 108 + c] *= inv;
    } else if (c < 108) {
        out_mol[(size_t)m * 108 + c] = f_mol[(size_t)m * 8 + (c - 100)];
    }
}

// ================= cooperative fused kernel =================

__global__ __launch_bounds__(THREADS, 4) void fused(
    const float* __restrict__ fa, const float* __restrict__ fb, const float* __restrict__ fm,
    const float* __restrict__ Wi, const float* __restrict__ Wh, const float* __restrict__ Wo,
    const int* __restrict__ a2b, const int* __restrict__ b2a,
    const int* __restrict__ b2revb, const int* __restrict__ moid,
    unsigned short* __restrict__ wfi, unsigned short* __restrict__ wfh,
    unsigned short* __restrict__ wfo, unsigned short* __restrict__ amsg,
    unsigned short* __restrict__ inp, unsigned short* __restrict__ msgA,
    unsigned short* __restrict__ msgB,
    float* __restrict__ atom_h, float* __restrict__ out_mol,
    int A, int B, int Mmol)
{
    __shared__ char smem[25600];
    __shared__ int mids[64];
    cg::grid_group grid = cg::this_grid();
    const int tid = threadIdx.x;
    const int gt = blockIdx.x * THREADS + tid;
    const int nth = gridDim.x * THREADS;
    const int gB = (B + 63) >> 6, gA = (A + 63) >> 6;

    // phase 0: weight packs + zero out_mol
    for (int i = gt; i < 119 * 64; i += nth) prep_item(i, Wi, Wh, Wo, wfi, wfh, wfo);
    for (int i = gt; i * 4 < Mmol * 108; i += nth)
        *(f32x4*)&out_mol[(size_t)i * 4] = (f32x4){0.f, 0.f, 0.f, 0.f};
    grid.sync();

    // phase 1: inp = relu(f_bonds @ W_i)
    for (int tb = blockIdx.x; tb < gB; tb += gridDim.x)
        gemm_in_tile(tb * 64, tid, fb, wfi, inp, B, smem);
    grid.sync();

    // phase 2: amsg = gather_sum(inp)
    for (int t = gt; t < A * 16; t += nth) gather_item(t, inp, a2b, amsg);
    grid.sync();

    // phase 3: msgA
    for (int tb = blockIdx.x; tb < gB; tb += gridDim.x)
        gemm_msg_tile(tb * 64, tid, amsg, inp, b2a, b2revb, wfh, inp, msgA, B, 0, smem);
    grid.sync();

    // phase 4: amsg = gather_sum(msgA)
    for (int t = gt; t < A * 16; t += nth) gather_item(t, msgA, a2b, amsg);
    grid.sync();

    // phase 5: msgB
    for (int tb = blockIdx.x; tb < gB; tb += gridDim.x)
        gemm_msg_tile(tb * 64, tid, amsg, msgA, b2a, b2revb, wfh, inp, msgB, B, 1, smem);
    grid.sync();

    // phase 6: atom_h + molecule partial sums
    for (int tb = blockIdx.x; tb < gA; tb += gridDim.x)
        gemm_out_tile(tb * 64, tid, fa, msgB, a2b, wfo, moid, atom_h, out_mol, A, smem, mids);
    grid.sync();

    // phase 7: finalize molecules
    for (int i = gt; i < Mmol * 128; i += nth)
        finalize_item(i >> 7, i & 127, out_mol, fm, moid, A);
}

// ================= fallback standalone kernels (R8 path) =================

__global__ __launch_bounds__(64) void prep(
    const float* __restrict__ Wi, const float* __restrict__ Wh, const float* __restrict__ Wo,
    unsigned short* __restrict__ wfi, unsigned short* __restrict__ wfh,
    unsigned short* __restrict__ wfo, float* __restrict__ out_mol, int nmol_floats)
{
    int bid = blockIdx.x;
    int l = threadIdx.x;
    if (bid < 119) {
        prep_item(bid * 64 + l, Wi, Wh, Wo, wfi, wfh, wfo);
    } else {
        int idx = (bid - 119) * 64 + l;
        int stride = (gridDim.x - 119) * 64;
        for (int i = idx; i * 4 < nmol_floats; i += stride)
            *(f32x4*)&out_mol[(size_t)i * 4] = (f32x4){0.f, 0.f, 0.f, 0.f};
    }
}

__global__ __launch_bounds__(THREADS) void gather_sum_bf16(
    const unsigned short* __restrict__ msg, const int* __restrict__ a2b,
    unsigned short* __restrict__ amsg, int A)
{
    int t = blockIdx.x * THREADS + threadIdx.x;
    if (t >= A * 16) return;
    gather_item(t, msg, a2b, amsg);
}

__global__ __launch_bounds__(THREADS, 2) void gemm_in(
    const float* __restrict__ fb, const unsigned short* __restrict__ wf,
    unsigned short* __restrict__ Y, int M)
{
    __shared__ char smem[64 * 168 * 2];
    gemm_in_tile(blockIdx.x * 64, threadIdx.x, fb, wf, Y, M, smem);
}

__global__ __launch_bounds__(THREADS, 2) void gemm_msg(
    const unsigned short* __restrict__ amsg, const unsigned short* __restrict__ msg,
    const int* __restrict__ b2a, const int* __restrict__ b2revb,
    const unsigned short* __restrict__ wf, const unsigned short* __restrict__ bias,
    unsigned short* __restrict__ Y, int M, int last)
{
    __shared__ char smem[64 * 136 * 2];
    gemm_msg_tile(blockIdx.x * 64, threadIdx.x, amsg, msg, b2a, b2revb, wf, bias, Y, M, last, smem);
}

__global__ __launch_bounds__(THREADS, 2) void gemm_out(
    const float* __restrict__ fa, const unsigned short* __restrict__ msg,
    const int* __restrict__ a2b, const unsigned short* __restrict__ wf,
    const int* __restrict__ mol_id, float* __restrict__ Y,
    float* __restrict__ out_mol, int M)
{
    __shared__ char smem[64 * 100 * 4];
    __shared__ int mids[64];
    gemm_out_tile(blockIdx.x * 64, threadIdx.x, fa, msg, a2b, wf, mol_id, Y, out_mol, M, smem, mids);
}

__global__ __launch_bounds__(128) void finalize(
    float* __restrict__ out_mol, const float* __restrict__ f_mol,
    const int* __restrict__ mol_id, int n_atoms)
{
    finalize_item(blockIdx.x, threadIdx.x, out_mol, f_mol, mol_id, n_atoms);
}

// ================= launcher =================

extern "C" void kernel_launch(void* const* d_in, const int* in_sizes, int n_in,
                              void* d_out, int out_size, void* d_ws, size_t ws_size,
                              hipStream_t stream)
{
    const float* f_atoms = (const float*)d_in[0];
    const float* f_bonds = (const float*)d_in[1];
    const float* f_mol   = (const float*)d_in[2];
    const float* W_i     = (const float*)d_in[3];
    const float* W_h     = (const float*)d_in[4];
    const float* W_o     = (const float*)d_in[5];
    const int* a2b    = (const int*)d_in[6];
    const int* b2a    = (const int*)d_in[7];
    const int* b2revb = (const int*)d_in[8];
    const int* mol_id = (const int*)d_in[9];

    int A    = in_sizes[0] / 133;
    int B    = in_sizes[1] / 147;
    int Mmol = in_sizes[2] / 8;

    unsigned short* wsu = (unsigned short*)d_ws;
    unsigned short* wfi  = wsu;                     // 35*512
    unsigned short* wfh  = wfi + 35 * 512;          // 28*512
    unsigned short* wfo  = wfh + 28 * 512;          // 56*512
    unsigned short* amsg = wfo + 56 * 512;          // (A,MS)
    unsigned short* inp  = amsg + (size_t)A * MS;   // (B,MS)
    unsigned short* msgA = inp  + (size_t)B * MS;
    unsigned short* msgB = msgA + (size_t)B * MS;

    float* out     = (float*)d_out;
    float* out_mol = out;
    float* atom_h  = out + (size_t)Mmol * 108;

    // cooperative grid size: occupancy-clamped, cached (query is capture-safe)
    static int coop_grid = -2;   // -2 = not probed, -1 = unsupported
    if (coop_grid == -2) {
        int nb = 0;
        hipError_t e = hipOccupancyMaxActiveBlocksPerMultiprocessor(&nb, fused, THREADS, 0);
        coop_grid = (e == hipSuccess && nb > 0) ? (nb > 8 ? 8 : nb) * 256 : -1;
    }

    if (coop_grid > 0) {
        void* args[] = {
            (void*)&f_atoms, (void*)&f_bonds, (void*)&f_mol,
            (void*)&W_i, (void*)&W_h, (void*)&W_o,
            (void*)&a2b, (void*)&b2a, (void*)&b2revb, (void*)&mol_id,
            (void*)&wfi, (void*)&wfh, (void*)&wfo, (void*)&amsg,
            (void*)&inp, (void*)&msgA, (void*)&msgB,
            (void*)&atom_h, (void*)&out_mol,
            (void*)&A, (void*)&B, (void*)&Mmol
        };
        hipError_t rc = hipLaunchCooperativeKernel(fused, dim3(coop_grid), dim3(THREADS),
                                                   args, 0, stream);
        if (rc == hipSuccess) return;
        (void)hipGetLastError();   // clear; fall through to multi-dispatch path
        coop_grid = -1;            // don't retry
    }

    // ---- fallback: R8 7-dispatch path ----
    dim3 blk(THREADS);
    int gB = (B + 63) / 64;
    int gA = (A + 63) / 64;
    int gg = (A * 16 + THREADS - 1) / THREADS;

    prep<<<119 + 256, dim3(64), 0, stream>>>(W_i, W_h, W_o, wfi, wfh, wfo,
                                             out_mol, Mmol * 108);
    gemm_in<<<gB, blk, 0, stream>>>(f_bonds, wfi, inp, B);
    gather_sum_bf16<<<gg, blk, 0, stream>>>(inp, a2b, amsg, A);
    gemm_msg<<<gB, blk, 0, stream>>>(amsg, inp, b2a, b2revb, wfh, inp, msgA, B, 0);
    gather_sum_bf16<<<gg, blk, 0, stream>>>(msgA, a2b, amsg, A);
    gemm_msg<<<gB, blk, 0, stream>>>(amsg, msgA, b2a, b2revb, wfh, inp, msgB, B, 1);
    gemm_out<<<gA, blk, 0, stream>>>(f_atoms, msgB, a2b, wfo, mol_id, atom_h, out_mol, A);
    finalize<<<Mmol, dim3(128), 0, stream>>>(out_mol, f_mol, mol_id, A);
}

// Round 10
// 989.634 us; speedup vs baseline: 1.9984x; 1.9984x over previous
//
#include <hip/hip_runtime.h>

#define THREADS 256
#define MS 128   // message row stride in shorts (256 B, cache-line aligned)

typedef __bf16 bf16x8 __attribute__((ext_vector_type(8)));
typedef float f32x4 __attribute__((ext_vector_type(4)));
typedef float f32x4u __attribute__((ext_vector_type(4), aligned(4)));

__device__ __forceinline__ unsigned short f2b(float x) {
    unsigned int u = __float_as_uint(x);
    u = (u + 0x7FFFu + ((u >> 16) & 1u)) >> 16;
    return (unsigned short)u;
}
__device__ __forceinline__ float b2f(unsigned short h) {
    return __uint_as_float(((unsigned int)h) << 16);
}
__device__ __forceinline__ bf16x8 as_bf(uint4 q) {
    union { uint4 q; bf16x8 v; } u; u.q = q; return u.v;
}

// ---- pack bodies ----
// lane l, reg j -> B[k = kc*32 + (l>>4)*8 + j][n = nt*16 + (l&15)]
__device__ __forceinline__ void pack_body(const float* __restrict__ W,
                                          unsigned short* __restrict__ out,
                                          int K, int bid, int l)
{
    int kc = bid / 7, nt = bid - kc * 7;
    int k0 = kc * 32 + (l >> 4) * 8;
    int n = nt * 16 + (l & 15);
    unsigned short v[8];
    #pragma unroll
    for (int j = 0; j < 8; ++j) {
        int k = k0 + j;
        float x = (k < K && n < 100) ? W[(size_t)k * 100 + n] : 0.f;
        v[j] = f2b(x);
    }
    *(uint4*)&out[((size_t)bid * 64 + l) * 8] = *(uint4*)v;
}

// W_o permuted k: k<100 -> row 133+k (amsg), 100..111 zero, 112..244 -> row k-112 (f_atoms)
__device__ __forceinline__ void pack_wo_body(const float* __restrict__ W,
                                             unsigned short* __restrict__ out,
                                             int bid, int l)
{
    int kc = bid / 7, nt = bid - kc * 7;
    int k0 = kc * 32 + (l >> 4) * 8;
    int n = nt * 16 + (l & 15);
    unsigned short v[8];
    #pragma unroll
    for (int j = 0; j < 8; ++j) {
        int k = k0 + j;
        float x = 0.f;
        if (n < 100) {
            if (k < 100)                  x = W[(size_t)(133 + k) * 100 + n];
            else if (k >= 112 && k < 245) x = W[(size_t)(k - 112) * 100 + n];
        }
        v[j] = f2b(x);
    }
    *(uint4*)&out[((size_t)bid * 64 + l) * 8] = *(uint4*)v;
}

// ---- prep: all W packs + zero out_mol accumulator, one dispatch ----
__global__ __launch_bounds__(64) void prep(
    const float* __restrict__ Wi, const float* __restrict__ Wh, const float* __restrict__ Wo,
    unsigned short* __restrict__ wfi, unsigned short* __restrict__ wfh,
    unsigned short* __restrict__ wfo, float* __restrict__ out_mol, int nmol_floats)
{
    int bid = blockIdx.x;
    int l = threadIdx.x;
    if (bid < 35) {
        pack_body(Wi, wfi, 147, bid, l);
    } else if (bid < 63) {
        pack_body(Wh, wfh, 100, bid - 35, l);
    } else if (bid < 119) {
        pack_wo_body(Wo, wfo, bid - 63, l);
    } else {
        int idx = (bid - 119) * 64 + l;
        int stride = (gridDim.x - 119) * 64;
        for (int i = idx; i * 4 < nmol_floats; i += stride)
            *(f32x4*)&out_mol[(size_t)i * 4] = (f32x4){0.f, 0.f, 0.f, 0.f};
    }
}

// ---- a_message[a] = sum_j message[a2b[a][j]] (bf16, stride MS) ----
// chunks 14,15 written zero so consumers can read [0,256) safely
__global__ __launch_bounds__(THREADS) void gather_sum_bf16(
    const unsigned short* __restrict__ msg, const int* __restrict__ a2b,
    unsigned short* __restrict__ amsg, int A)
{
    int t = blockIdx.x * THREADS + threadIdx.x;
    if (t >= A * 16) return;
    int a = t >> 4;
    int c = t & 15;
    if (c >= 14) {
        *(uint4*)&amsg[(size_t)a * MS + c * 8] = make_uint4(0u, 0u, 0u, 0u);
        return;
    }
    const int* nb = a2b + (size_t)a * 6;
    float s[8];
    #pragma unroll
    for (int e = 0; e < 8; ++e) s[e] = 0.f;
    #pragma unroll
    for (int j = 0; j < 6; ++j) {
        uint4 v = *(const uint4*)&msg[(size_t)nb[j] * MS + c * 8];
        const unsigned short* pv = (const unsigned short*)&v;
        #pragma unroll
        for (int e = 0; e < 8; ++e) s[e] += b2f(pv[e]);
    }
    unsigned short r[8];
    #pragma unroll
    for (int e = 0; e < 8; ++e) r[e] = f2b(s[e]);
    *(uint4*)&amsg[(size_t)a * MS + c * 8] = *(uint4*)r;
}

// ---- inp = relu(f_bonds @ W_i): coalesced LDS staging of the 64x147 fp32 tile ----
__global__ __launch_bounds__(THREADS, 2) void gemm_in(
    const float* __restrict__ fb, const unsigned short* __restrict__ wf,
    unsigned short* __restrict__ Y, int M)
{
    constexpr int KS = 168;                       // 160 k-cols + 8 pad (shorts)
    __shared__ char smem[64 * KS * 2];            // Xs (bf16) then reused as Os (stride 136)
    unsigned short* Xs = (unsigned short*)smem;
    unsigned short* Os = (unsigned short*)smem;

    const int tid = threadIdx.x;
    const int l = tid & 63, w = tid >> 6;
    const int quad = l >> 4, c15 = l & 15;
    const int row0 = blockIdx.x * 64;

    for (int t = tid; t < 64 * 20; t += THREADS) {
        int rl = t / 20, c = t - rl * 20;
        int rr = min(row0 + rl, M - 1);
        const float* rowp = fb + (size_t)rr * 147 + c * 8;
        unsigned short tt[8];
        if (c < 18) {
            f32x4u x0 = *(const f32x4u*)(rowp);
            f32x4u x1 = *(const f32x4u*)(rowp + 4);
            #pragma unroll
            for (int e = 0; e < 4; ++e) { tt[e] = f2b(x0[e]); tt[4 + e] = f2b(x1[e]); }
        } else if (c == 18) {
            #pragma unroll
            for (int j = 0; j < 8; ++j)
                tt[j] = (j < 3) ? f2b(rowp[j]) : (unsigned short)0;
        } else {
            #pragma unroll
            for (int j = 0; j < 8; ++j) tt[j] = 0;
        }
        *(uint4*)&Xs[(size_t)rl * KS + c * 8] = *(uint4*)tt;
    }
    __syncthreads();

    f32x4 acc[7];
    #pragma unroll
    for (int nt = 0; nt < 7; ++nt) acc[nt] = (f32x4){0.f, 0.f, 0.f, 0.f};
    const unsigned short* xrow = Xs + (size_t)(w * 16 + c15) * KS + quad * 8;
    #pragma unroll
    for (int kc = 0; kc < 5; ++kc) {
        bf16x8 av = *(const bf16x8*)(xrow + kc * 32);
        #pragma unroll
        for (int nt = 0; nt < 7; ++nt) {
            uint4 bq = *(const uint4*)&wf[((size_t)(kc * 7 + nt) * 64 + l) * 8];
            acc[nt] = __builtin_amdgcn_mfma_f32_16x16x32_bf16(av, as_bf(bq), acc[nt], 0, 0, 0);
        }
    }
    __syncthreads();

    #pragma unroll
    for (int nt = 0; nt < 7; ++nt)
        #pragma unroll
        for (int reg = 0; reg < 4; ++reg)
            Os[(w * 16 + quad * 4 + reg) * 136 + nt * 16 + c15] = f2b(fmaxf(acc[nt][reg], 0.f));
    __syncthreads();

    for (int t = tid; t < 64 * 16; t += THREADS) {
        int rl = t >> 4, c = t & 15;
        int rr = row0 + rl;
        if (rr < M) {
            uint4 o = (c < 14) ? *(const uint4*)&Os[rl * 136 + c * 8]
                               : make_uint4(0u, 0u, 0u, 0u);
            *(uint4*)&Y[(size_t)rr * MS + c * 8] = o;
        }
    }
}

// ---- message = relu(inp + amsg[b2a]@W - msg[b2revb]@W), dual-MFMA linearity ----
// gathered A-operands staged through LDS with full-row cooperative reads
// (4 whole 256-B rows per VMEM instr instead of 16 scattered 64-B segments),
// chunk-XOR swizzle keeps the MFMA-phase ds_read_b128 at free 2-way conflicts.
// last=1: skip zero-chunk stores (consumer reads c<14 only)
__global__ __launch_bounds__(THREADS, 2) void gemm_msg(
    const unsigned short* __restrict__ amsg, const unsigned short* __restrict__ msg,
    const int* __restrict__ b2a, const int* __restrict__ b2revb,
    const unsigned short* __restrict__ wf, const unsigned short* __restrict__ bias,
    unsigned short* __restrict__ Y, int M, int last)
{
    __shared__ char smem[64 * 256 * 2];                    // As | Bs (16 KB each)
    unsigned short* As = (unsigned short*)smem;            // [64][128], swizzled chunks
    unsigned short* Bs = (unsigned short*)(smem + 64 * 256);
    unsigned short* Os = (unsigned short*)smem;            // [64][136] overlay after MFMA

    const int tid = threadIdx.x;
    const int l = tid & 63, w = tid >> 6;
    const int quad = l >> 4, c15 = l & 15;
    const int row0 = blockIdx.x * 64;

    // stage: 16 threads cooperatively copy each gathered row (chunks 0..15)
    for (int t = tid; t < 64 * 16; t += THREADS) {
        int rl = t >> 4, c = t & 15;
        int rr = min(row0 + rl, M - 1);
        int sc = (c ^ (rl & 7)) * 8;                       // swizzled chunk offset
        *(uint4*)&As[rl * 128 + sc] = *(const uint4*)&amsg[(size_t)b2a[rr]    * MS + c * 8];
        *(uint4*)&Bs[rl * 128 + sc] = *(const uint4*)&msg [(size_t)b2revb[rr] * MS + c * 8];
    }
    __syncthreads();

    f32x4 acc1[7], acc2[7];
    #pragma unroll
    for (int nt = 0; nt < 7; ++nt) {
        acc1[nt] = (f32x4){0.f, 0.f, 0.f, 0.f};
        acc2[nt] = (f32x4){0.f, 0.f, 0.f, 0.f};
    }
    const int r = w * 16 + c15;
    const int rx = r & 7;
    #pragma unroll
    for (int kc = 0; kc < 4; ++kc) {
        int chk = ((kc * 4 + quad) ^ rx) * 8;
        bf16x8 av = *(const bf16x8*)&As[r * 128 + chk];
        bf16x8 bv = *(const bf16x8*)&Bs[r * 128 + chk];
        #pragma unroll
        for (int nt = 0; nt < 7; ++nt) {
            uint4 bq = *(const uint4*)&wf[((size_t)(kc * 7 + nt) * 64 + l) * 8];
            acc1[nt] = __builtin_amdgcn_mfma_f32_16x16x32_bf16(av, as_bf(bq), acc1[nt], 0, 0, 0);
            acc2[nt] = __builtin_amdgcn_mfma_f32_16x16x32_bf16(bv, as_bf(bq), acc2[nt], 0, 0, 0);
        }
    }
    __syncthreads();   // done reading As/Bs; reuse as Os

    #pragma unroll
    for (int nt = 0; nt < 7; ++nt)
        #pragma unroll
        for (int reg = 0; reg < 4; ++reg)
            Os[(w * 16 + quad * 4 + reg) * 136 + nt * 16 + c15] = f2b(acc1[nt][reg] - acc2[nt][reg]);
    __syncthreads();

    for (int t = tid; t < 64 * 16; t += THREADS) {
        int rl = t >> 4, c = t & 15;
        int rr = row0 + rl;
        if (rr >= M) continue;
        if (c < 14) {
            uint4 o = *(const uint4*)&Os[rl * 136 + c * 8];
            uint4 bq = *(const uint4*)&bias[(size_t)rr * MS + c * 8];
            const unsigned short* po = (const unsigned short*)&o;
            const unsigned short* pq = (const unsigned short*)&bq;
            unsigned short res[8];
            #pragma unroll
            for (int e = 0; e < 8; ++e)
                res[e] = f2b(fmaxf(b2f(po[e]) + b2f(pq[e]), 0.f));
            *(uint4*)&Y[(size_t)rr * MS + c * 8] = *(uint4*)res;
        } else if (!last) {
            *(uint4*)&Y[(size_t)rr * MS + c * 8] = make_uint4(0u, 0u, 0u, 0u);
        }
    }
}

// ---- atom_h = relu(concat(gather_sum(msg), f_atoms)_perm @ W_o_perm) ----
// LDS: Xs gathered-amsg tile (17.4 KB) / Os fp32 overlay (25.6 KB);
// f_atoms A-fragments direct per-lane from global
__global__ __launch_bounds__(THREADS, 2) void gemm_out(
    const float* __restrict__ fa, const unsigned short* __restrict__ msg,
    const int* __restrict__ a2b, const unsigned short* __restrict__ wf,
    const int* __restrict__ mol_id, float* __restrict__ Y,
    float* __restrict__ out_mol, int M)
{
    constexpr int XSS = 136;                      // Xs row stride in shorts (128 + 8 pad)
    __shared__ char smem[64 * 100 * 4];           // max(Xs 17408, Os 25600)
    __shared__ int mids[64];
    unsigned short* Xs = (unsigned short*)smem;   // [64][136] bf16: gathered amsg, k 0..111 (+pad)
    float* Os = (float*)smem;                     // [64][100] fp32 overlay after MFMA

    const int tid = threadIdx.x;
    const int l = tid & 63, w = tid >> 6;
    const int quad = l >> 4, c15 = l & 15;
    const int row0 = blockIdx.x * 64;

    if (tid < 64) {
        int rr = row0 + tid;
        mids[tid] = (rr < M) ? mol_id[rr] : -1;
    }

    // f_atoms direct A-fragments: kc 3..7 -> cols kc*32 + quad*8 - 112 .. +7
    uint4 af[5];
    {
        const int r = w * 16 + c15;
        const int rr = min(row0 + r, M - 1);
        const float* fap = fa + (size_t)rr * 133;
        #pragma unroll
        for (int kk = 0; kk < 5; ++kk) {
            int col0 = (kk + 3) * 32 + quad * 8 - 112;
            unsigned short tt[8];
            if (col0 >= 0 && col0 + 7 < 133) {        // fast path (covers all interior)
                f32x4u x0 = *(const f32x4u*)(fap + col0);
                f32x4u x1 = *(const f32x4u*)(fap + col0 + 4);
                #pragma unroll
                for (int e = 0; e < 4; ++e) { tt[e] = f2b(x0[e]); tt[4 + e] = f2b(x1[e]); }
            } else {                                   // edge: per-element guard (or unused kc3 q0/1)
                #pragma unroll
                for (int j = 0; j < 8; ++j) {
                    int cc = col0 + j;
                    tt[j] = (cc >= 0 && cc < 133) ? f2b(fap[cc]) : (unsigned short)0;
                }
            }
            af[kk] = *(uint4*)tt;
        }
    }

    // gather staging: 64 rows x 16 chunks -> Xs (chunks 14,15 zero)
    for (int t = tid; t < 64 * 16; t += THREADS) {
        int rl = t >> 4, c = t & 15;
        int rr = min(row0 + rl, M - 1);
        uint4 o = make_uint4(0u, 0u, 0u, 0u);
        if (c < 14) {
            const int* nb = a2b + (size_t)rr * 6;
            float s[8];
            #pragma unroll
            for (int e = 0; e < 8; ++e) s[e] = 0.f;
            #pragma unroll
            for (int j = 0; j < 6; ++j) {
                uint4 v = *(const uint4*)&msg[(size_t)nb[j] * MS + c * 8];
                const unsigned short* pv = (const unsigned short*)&v;
                #pragma unroll
                for (int e = 0; e < 8; ++e) s[e] += b2f(pv[e]);
            }
            unsigned short r8[8];
            #pragma unroll
            for (int e = 0; e < 8; ++e) r8[e] = f2b(s[e]);
            o = *(uint4*)r8;
        }
        *(uint4*)&Xs[rl * XSS + c * 8] = o;
    }
    __syncthreads();

    f32x4 acc[7];
    #pragma unroll
    for (int nt = 0; nt < 7; ++nt) acc[nt] = (f32x4){0.f, 0.f, 0.f, 0.f};
    const unsigned short* xrow = Xs + (size_t)(w * 16 + c15) * XSS + quad * 8;
    #pragma unroll
    for (int kc = 0; kc < 8; ++kc) {
        bf16x8 av;
        if (kc < 3)       av = *(const bf16x8*)(xrow + kc * 32);            // amsg k 0..95
        else if (kc == 3) av = (quad < 2) ? *(const bf16x8*)(xrow + 3 * 32) // k 96..111
                                          : as_bf(af[0]);                   // f_atoms 0..15
        else              av = as_bf(af[kc - 3]);                           // f_atoms 16..132
        #pragma unroll
        for (int nt = 0; nt < 7; ++nt) {
            uint4 bq = *(const uint4*)&wf[((size_t)(kc * 7 + nt) * 64 + l) * 8];
            acc[nt] = __builtin_amdgcn_mfma_f32_16x16x32_bf16(av, as_bf(bq), acc[nt], 0, 0, 0);
        }
    }
    __syncthreads();   // done reading Xs; reuse as Os

    #pragma unroll
    for (int nt = 0; nt < 7; ++nt) {
        int n = nt * 16 + c15;
        if (n < 100) {
            #pragma unroll
            for (int reg = 0; reg < 4; ++reg)
                Os[(w * 16 + quad * 4 + reg) * 100 + n] = fmaxf(acc[nt][reg], 0.f);
        }
    }
    __syncthreads();

    for (int t = tid; t < 64 * 25; t += THREADS) {
        int rl = t / 25, c = t - rl * 25;
        int rr = row0 + rl;
        if (rr < M)
            *(f32x4*)&Y[(size_t)rr * 100 + c * 4] = *(const f32x4*)&Os[rl * 100 + c * 4];
    }

    // per-molecule partial sums (mol_id contiguous): 1-2 atomics per (mol,col)
    if (tid < 100) {
        int c = tid;
        float s = 0.f;
        int cur = mids[0];
        #pragma unroll 1
        for (int rl = 0; rl < 64; ++rl) {
            int mid = mids[rl];
            if (mid != cur) {
                if (cur >= 0) atomicAdd(&out_mol[(size_t)cur * 108 + c], s);
                s = 0.f;
                cur = mid;
            }
            if (mid < 0) break;
            s += Os[rl * 100 + c];
        }
        if (cur >= 0) atomicAdd(&out_mol[(size_t)cur * 108 + c], s);
    }
}

// ---- finalize: divide by count, append f_mol ----
__global__ __launch_bounds__(128) void finalize(
    float* __restrict__ out_mol, const float* __restrict__ f_mol,
    const int* __restrict__ mol_id, int n_atoms)
{
    int m = blockIdx.x;
    int lo = 0, hi = n_atoms;
    while (lo < hi) { int mid = (lo + hi) >> 1; if (mol_id[mid] < m) lo = mid + 1; else hi = mid; }
    int lo2 = lo, hi2 = n_atoms;
    while (lo2 < hi2) { int mid = (lo2 + hi2) >> 1; if (mol_id[mid] < m + 1) lo2 = mid + 1; else hi2 = mid; }
    float inv = 1.0f / fmaxf((float)(lo2 - lo), 1.0f);
    int c = threadIdx.x;
    if (c < 100) {
        out_mol[(size_t)m * 108 + c] *= inv;
    } else if (c < 108) {
        out_mol[(size_t)m * 108 + c] = f_mol[(size_t)m * 8 + (c - 100)];
    }
}

extern "C" void kernel_launch(void* const* d_in, const int* in_sizes, int n_in,
                              void* d_out, int out_size, void* d_ws, size_t ws_size,
                              hipStream_t stream)
{
    const float* f_atoms = (const float*)d_in[0];
    const float* f_bonds = (const float*)d_in[1];
    const float* f_mol   = (const float*)d_in[2];
    const float* W_i     = (const float*)d_in[3];
    const float* W_h     = (const float*)d_in[4];
    const float* W_o     = (const float*)d_in[5];
    const int* a2b    = (const int*)d_in[6];
    const int* b2a    = (const int*)d_in[7];
    const int* b2revb = (const int*)d_in[8];
    const int* mol_id = (const int*)d_in[9];

    const int A    = in_sizes[0] / 133;
    const int B    = in_sizes[1] / 147;
    const int Mmol = in_sizes[2] / 8;

    unsigned short* wsu = (unsigned short*)d_ws;
    unsigned short* wfi  = wsu;                     // 35*512
    unsigned short* wfh  = wfi + 35 * 512;          // 28*512
    unsigned short* wfo  = wfh + 28 * 512;          // 56*512
    unsigned short* amsg = wfo + 56 * 512;          // (A,MS)
    unsigned short* inp  = amsg + (size_t)A * MS;   // (B,MS)
    unsigned short* msgA = inp  + (size_t)B * MS;
    unsigned short* msgB = msgA + (size_t)B * MS;

    float* out     = (float*)d_out;
    float* out_mol = out;
    float* atom_h  = out + (size_t)Mmol * 108;

    dim3 blk(THREADS);
    int gB = (B + 63) / 64;
    int gA = (A + 63) / 64;
    int gg = (A * 16 + THREADS - 1) / THREADS;

    prep<<<119 + 256, dim3(64), 0, stream>>>(W_i, W_h, W_o, wfi, wfh, wfo,
                                             out_mol, Mmol * 108);

    gemm_in<<<gB, blk, 0, stream>>>(f_bonds, wfi, inp, B);

    gather_sum_bf16<<<gg, blk, 0, stream>>>(inp, a2b, amsg, A);
    gemm_msg<<<gB, blk, 0, stream>>>(amsg, inp, b2a, b2revb, wfh, inp, msgA, B, 0);

    gather_sum_bf16<<<gg, blk, 0, stream>>>(msgA, a2b, amsg, A);
    gemm_msg<<<gB, blk, 0, stream>>>(amsg, msgA, b2a, b2revb, wfh, inp, msgB, B, 1);

    gemm_out<<<gA, blk, 0, stream>>>(f_atoms, msgB, a2b, wfo, mol_id, atom_h, out_mol, A);

    finalize<<<Mmol, dim3(128), 0, stream>>>(out_mol, f_mol, mol_id, A);
}